// Round 1
// baseline (1152.028 us; speedup 1.0000x reference)
//
#include <hip/hip_runtime.h>
#include <math.h>

#define N_SAMP   32768
#define WINDOW   512
#define STEP     256
#define NFRAMES  127      // (32768-512)/256 + 1
#define NB       4

// ws layout (float granularity)
#define WS_WF   0               // 4*127*512 = 260096 floats
#define WS_PV   260096          // 2032 floats  (partial max values)
#define WS_PI   262128          // 2032 ints    (partial max indices)
#define WS_M    264160          // 508 ints     (argmax per (b,f))
#define WS_OUT  264704          // 131072 floats (summed positioned)
#define WS_TOTAL (WS_OUT + NB*N_SAMP)

// ---------------------------------------------------------------- kernel A
// wf[b,f,w] = hamming(w) * recon[b, f*256 + w]
__global__ __launch_bounds__(256) void k_wf(const float* __restrict__ recon,
                                            float* __restrict__ wf) {
    int e = blockIdx.x * 256 + threadIdx.x;
    if (e >= NB * NFRAMES * WINDOW) return;
    int w  = e & 511;
    int bf = e >> 9;
    int f  = bf % NFRAMES;
    int b  = bf / NFRAMES;
    float ham = 0.54f - 0.46f * (float)cos((double)w * (M_PI / 256.0));
    wf[e] = ham * recon[b * N_SAMP + f * STEP + w];
}

// ---------------------------------------------------------------- kernel B
// per-(b,f,tile) partial argmax of fm[t] = sum_w wf[w]*tgt[t-w]
__global__ __launch_bounds__(256) void k_argmax(const float* __restrict__ tgt,
                                                const float* __restrict__ wf,
                                                float* __restrict__ pv,
                                                int*   __restrict__ pi) {
    __shared__ __align__(16) float s_wf[512];
    __shared__ __align__(16) float s_tg[1540];
    __shared__ float rv[256];
    __shared__ int   ri[256];
    const int tid  = threadIdx.x;
    const int tile = blockIdx.x & 3;
    const int bf   = blockIdx.x >> 2;
    const int b    = bf / NFRAMES;
    const float* tb = tgt + b * N_SAMP;

    if (tid < 128)
        ((float4*)s_wf)[tid] = ((const float4*)(wf + bf * 512))[tid];

    float best = -3.4e38f;
    int   bidx = 0;

    for (int p = 0; p < 8; ++p) {
        int t0   = tile * 8192 + p * 1024;
        int base = t0 - 516;
        __syncthreads();
        for (int e4 = tid; e4 < 385; e4 += 256) {
            int g = base + 4 * e4;
            float4 v;
            if (g >= 0) v = *(const float4*)(tb + g);
            else        v = make_float4(0.f, 0.f, 0.f, 0.f);
            *(float4*)(s_tg + 4 * e4) = v;
        }
        __syncthreads();

        float4 acc = make_float4(0.f, 0.f, 0.f, 0.f);
        float4 lo = *(float4*)(s_tg + 4 * tid + 512);
        float4 hi = *(float4*)(s_tg + 4 * tid + 516);
#pragma unroll 8
        for (int g = 0; g < 128; ++g) {
            float4 c = *(float4*)(s_wf + 4 * g);
            acc.x = fmaf(c.x, hi.x, acc.x); acc.x = fmaf(c.y, lo.w, acc.x);
            acc.x = fmaf(c.z, lo.z, acc.x); acc.x = fmaf(c.w, lo.y, acc.x);
            acc.y = fmaf(c.x, hi.y, acc.y); acc.y = fmaf(c.y, hi.x, acc.y);
            acc.y = fmaf(c.z, lo.w, acc.y); acc.y = fmaf(c.w, lo.z, acc.y);
            acc.z = fmaf(c.x, hi.z, acc.z); acc.z = fmaf(c.y, hi.y, acc.z);
            acc.z = fmaf(c.z, hi.x, acc.z); acc.z = fmaf(c.w, lo.w, acc.z);
            acc.w = fmaf(c.x, hi.w, acc.w); acc.w = fmaf(c.y, hi.z, acc.w);
            acc.w = fmaf(c.z, hi.y, acc.w); acc.w = fmaf(c.w, hi.x, acc.w);
            hi = lo;
            lo = *(float4*)(s_tg + 4 * tid + 508 - 4 * g);
        }
        int tbase = t0 + 4 * tid;
        if (acc.x > best) { best = acc.x; bidx = tbase; }
        if (acc.y > best) { best = acc.y; bidx = tbase + 1; }
        if (acc.z > best) { best = acc.z; bidx = tbase + 2; }
        if (acc.w > best) { best = acc.w; bidx = tbase + 3; }
    }

    rv[tid] = best; ri[tid] = bidx;
    __syncthreads();
    for (int s = 128; s > 0; s >>= 1) {
        if (tid < s) {
            float v2 = rv[tid + s]; int i2 = ri[tid + s];
            if (v2 > rv[tid] || (v2 == rv[tid] && i2 < ri[tid])) {
                rv[tid] = v2; ri[tid] = i2;
            }
        }
        __syncthreads();
    }
    if (tid == 0) { pv[blockIdx.x] = rv[0]; pi[blockIdx.x] = ri[0]; }
}

// ---------------------------------------------------------------- kernel C
__global__ __launch_bounds__(256) void k_reduce(const float* __restrict__ pv,
                                                const int* __restrict__ pi,
                                                int* __restrict__ marr) {
    int id = blockIdx.x * 256 + threadIdx.x;
    if (id >= NB * NFRAMES) return;
    float best = -3.4e38f; int bidx = 0x7fffffff;
    for (int t = 0; t < 4; ++t) {
        float v = pv[id * 4 + t]; int i = pi[id * 4 + t];
        if (v > best || (v == best && i < bidx)) { best = v; bidx = i; }
    }
    marr[id] = bidx;
}

// ---------------------------------------------------------------- kernel D
// positioned[b,t] += sum_f sum_w wf[f,w] * h_f[(t-w) mod 2n]
// h_f[j] = (1/2n) [ (-1)^j cos(n*theta) + sin(pi*Bj/D)/sin(pi*Aj/D) ]
//   Aj = j*(n+1) - m*n (exact in double), Bj = (2n-1)*Aj, D = 2n(n+1)
__global__ __launch_bounds__(256) void k_shift_acc(const float* __restrict__ wf,
                                                   const int* __restrict__ marr,
                                                   float* __restrict__ outacc) {
    __shared__ __align__(16) float s_wf[512];
    __shared__ __align__(16) float s_h[1540];
    const int tid   = threadIdx.x;
    const int cid   = blockIdx.x;
    const int fg    = cid & 3;
    const int chunk = (cid >> 2) & 31;
    const int b     = cid >> 7;
    const int t0    = chunk * 1024;
    const int f0    = fg * 32;
    const int nf    = (fg == 3) ? 31 : 32;

    float4 acc = make_float4(0.f, 0.f, 0.f, 0.f);
    const double invD = 1.0 / 2147549184.0;   // 1/(65536*32769)

    for (int u = 0; u < nf; ++u) {
        int f  = f0 + u;
        int bf = b * NFRAMES + f;
        __syncthreads();   // previous frame's conv finished before re-staging
        if (tid < 128)
            ((float4*)s_wf)[tid] = ((const float4*)(wf + bf * 512))[tid];

        int m = marr[bf];
        double md = (double)m;
        double cosn = cos(md * (M_PI / 32769.0));
        if (m & 1) cosn = -cosn;
        float cosnf = (float)cosn;

        for (int e = tid; e < 1540; e += 256) {
            int jj = t0 - 516 + e;
            int j  = jj & 65535;
            double A = (double)j * 32769.0 - md * 32768.0;  // exact integer
            float ratio;
            if (A == 0.0) {
                ratio = 65535.0f;                            // removable 0/0
            } else {
                double rA = A * invD;                        // |rA| < 1.0001
                double kA = rint(rA);
                double dA = rA - kA;
                double rB = (A * 65535.0) * invD;            // exact * invD
                double kB = rint(rB);
                double dB = rB - kB;
                float sA = sinf((float)(dA * M_PI));
                float sB = sinf((float)(dB * M_PI));
                if (((int)kA) & 1) sA = -sA;
                if (((long long)kB) & 1) sB = -sB;
                ratio = sB / sA;
            }
            float sj = (j & 1) ? -1.0f : 1.0f;
            s_h[e] = (1.0f / 65536.0f) * (sj * cosnf + ratio);
        }
        __syncthreads();

        float4 lo = *(float4*)(s_h + 4 * tid + 512);
        float4 hi = *(float4*)(s_h + 4 * tid + 516);
#pragma unroll 8
        for (int g = 0; g < 128; ++g) {
            float4 c = *(float4*)(s_wf + 4 * g);
            acc.x = fmaf(c.x, hi.x, acc.x); acc.x = fmaf(c.y, lo.w, acc.x);
            acc.x = fmaf(c.z, lo.z, acc.x); acc.x = fmaf(c.w, lo.y, acc.x);
            acc.y = fmaf(c.x, hi.y, acc.y); acc.y = fmaf(c.y, hi.x, acc.y);
            acc.y = fmaf(c.z, lo.w, acc.y); acc.y = fmaf(c.w, lo.z, acc.y);
            acc.z = fmaf(c.x, hi.z, acc.z); acc.z = fmaf(c.y, hi.y, acc.z);
            acc.z = fmaf(c.z, hi.x, acc.z); acc.z = fmaf(c.w, lo.w, acc.z);
            acc.w = fmaf(c.x, hi.w, acc.w); acc.w = fmaf(c.y, hi.z, acc.w);
            acc.w = fmaf(c.z, hi.y, acc.w); acc.w = fmaf(c.w, hi.x, acc.w);
            hi = lo;
            lo = *(float4*)(s_h + 4 * tid + 508 - 4 * g);
        }
    }

    float* ob = outacc + b * N_SAMP + t0 + 4 * tid;
    atomicAdd(ob + 0, acc.x);
    atomicAdd(ob + 1, acc.y);
    atomicAdd(ob + 2, acc.z);
    atomicAdd(ob + 3, acc.w);
}

// ---------------------------------------------------------------- kernel E
__global__ __launch_bounds__(256) void k_mse(const float* __restrict__ outacc,
                                             const float* __restrict__ tgt,
                                             float* __restrict__ out) {
    __shared__ float sred[4];
    int e = blockIdx.x * 256 + threadIdx.x;
    float d = outacc[e] - tgt[e];
    float v = d * d;
#pragma unroll
    for (int off = 32; off > 0; off >>= 1) v += __shfl_down(v, off, 64);
    int lane = threadIdx.x & 63, wid = threadIdx.x >> 6;
    if (lane == 0) sred[wid] = v;
    __syncthreads();
    if (threadIdx.x == 0) {
        float s = sred[0] + sred[1] + sred[2] + sred[3];
        atomicAdd(out, s * (1.0f / 131072.0f));
    }
}

// ---------------------------------------------------------------- launch
extern "C" void kernel_launch(void* const* d_in, const int* in_sizes, int n_in,
                              void* d_out, int out_size, void* d_ws, size_t ws_size,
                              hipStream_t stream) {
    const float* recon = (const float*)d_in[0];
    const float* tgt   = (const float*)d_in[1];
    float* out = (float*)d_out;
    float* W   = (float*)d_ws;

    float* wf     = W + WS_WF;
    float* pv     = W + WS_PV;
    int*   pi     = (int*)(W + WS_PI);
    int*   marr   = (int*)(W + WS_M);
    float* outacc = W + WS_OUT;

    hipMemsetAsync(out, 0, sizeof(float), stream);
    hipMemsetAsync(outacc, 0, NB * N_SAMP * sizeof(float), stream);

    k_wf<<<(NB * NFRAMES * WINDOW + 255) / 256, 256, 0, stream>>>(recon, wf);
    k_argmax<<<NB * NFRAMES * 4, 256, 0, stream>>>(tgt, wf, pv, pi);
    k_reduce<<<2, 256, 0, stream>>>(pv, pi, marr);
    k_shift_acc<<<512, 256, 0, stream>>>(wf, marr, outacc);
    k_mse<<<512, 256, 0, stream>>>(outacc, tgt, out);
}

// Round 2
// 1003.957 us; speedup vs baseline: 1.1475x; 1.1475x over previous
//
#include <hip/hip_runtime.h>
#include <math.h>

#define N_SAMP   32768
#define WINDOW   512
#define STEP     256
#define NFRAMES  127      // (32768-512)/256 + 1
#define NB       4

// ws layout (float granularity)
#define WS_WF   0               // 4*127*512 = 260096 floats
#define WS_PV   260096          // 4064 floats  (partial max values)
#define WS_PI   264160          // 4064 ints    (partial max indices)
#define WS_M    268224          // 508 ints     (argmax per (b,f))
#define WS_OUT  268736          // 131072 floats (summed positioned)

// ---------------------------------------------------------------- kernel A
// wf[b,f,w] = hamming(w) * recon[b, f*256 + w]
__global__ __launch_bounds__(256) void k_wf(const float* __restrict__ recon,
                                            float* __restrict__ wf) {
    int e = blockIdx.x * 256 + threadIdx.x;
    if (e >= NB * NFRAMES * WINDOW) return;
    int w  = e & 511;
    int bf = e >> 9;
    int f  = bf % NFRAMES;
    int b  = bf / NFRAMES;
    float ham = 0.54f - 0.46f * (float)cos((double)w * (M_PI / 256.0));
    wf[e] = ham * recon[b * N_SAMP + f * STEP + w];
}

// ---------------------------------------------------------------- kernel B
// per-(b,f,tile) partial argmax of fm[t] = sum_w wf[w]*tgt[t-w]
// coefficients read from global (wave-uniform -> scalar cache), NOT LDS.
__global__ __launch_bounds__(256) void k_argmax(const float* __restrict__ tgt,
                                                const float* __restrict__ wf,
                                                float* __restrict__ pv,
                                                int*   __restrict__ pi) {
    __shared__ __align__(16) float s_tg[1540];
    __shared__ float rv[256];
    __shared__ int   ri[256];
    const int tid  = threadIdx.x;
    const int tile = blockIdx.x & 7;
    const int bf   = blockIdx.x >> 3;
    const int b    = bf / NFRAMES;
    const float* tb = tgt + b * N_SAMP;
    const float4* __restrict__ wc = (const float4*)(wf + bf * 512);

    float best = -3.4e38f;
    int   bidx = 0;

    for (int p = 0; p < 4; ++p) {
        int t0   = tile * 4096 + p * 1024;
        int base = t0 - 516;
        __syncthreads();
        for (int e4 = tid; e4 < 385; e4 += 256) {
            int g = base + 4 * e4;
            float4 v;
            if (g >= 0) v = *(const float4*)(tb + g);
            else        v = make_float4(0.f, 0.f, 0.f, 0.f);
            *(float4*)(s_tg + 4 * e4) = v;
        }
        __syncthreads();

        float4 acc = make_float4(0.f, 0.f, 0.f, 0.f);
        float4 lo = *(float4*)(s_tg + 4 * tid + 512);
        float4 hi = *(float4*)(s_tg + 4 * tid + 516);
#pragma unroll 8
        for (int g = 0; g < 128; ++g) {
            float4 c = wc[g];
            acc.x = fmaf(c.x, hi.x, acc.x); acc.x = fmaf(c.y, lo.w, acc.x);
            acc.x = fmaf(c.z, lo.z, acc.x); acc.x = fmaf(c.w, lo.y, acc.x);
            acc.y = fmaf(c.x, hi.y, acc.y); acc.y = fmaf(c.y, hi.x, acc.y);
            acc.y = fmaf(c.z, lo.w, acc.y); acc.y = fmaf(c.w, lo.z, acc.y);
            acc.z = fmaf(c.x, hi.z, acc.z); acc.z = fmaf(c.y, hi.y, acc.z);
            acc.z = fmaf(c.z, hi.x, acc.z); acc.z = fmaf(c.w, lo.w, acc.z);
            acc.w = fmaf(c.x, hi.w, acc.w); acc.w = fmaf(c.y, hi.z, acc.w);
            acc.w = fmaf(c.z, hi.y, acc.w); acc.w = fmaf(c.w, hi.x, acc.w);
            hi = lo;
            lo = *(float4*)(s_tg + 4 * tid + 508 - 4 * g);
        }
        int tbase = t0 + 4 * tid;
        if (acc.x > best) { best = acc.x; bidx = tbase; }
        if (acc.y > best) { best = acc.y; bidx = tbase + 1; }
        if (acc.z > best) { best = acc.z; bidx = tbase + 2; }
        if (acc.w > best) { best = acc.w; bidx = tbase + 3; }
    }

    rv[tid] = best; ri[tid] = bidx;
    __syncthreads();
    for (int s = 128; s > 0; s >>= 1) {
        if (tid < s) {
            float v2 = rv[tid + s]; int i2 = ri[tid + s];
            if (v2 > rv[tid] || (v2 == rv[tid] && i2 < ri[tid])) {
                rv[tid] = v2; ri[tid] = i2;
            }
        }
        __syncthreads();
    }
    if (tid == 0) { pv[blockIdx.x] = rv[0]; pi[blockIdx.x] = ri[0]; }
}

// ---------------------------------------------------------------- kernel C
__global__ __launch_bounds__(256) void k_reduce(const float* __restrict__ pv,
                                                const int* __restrict__ pi,
                                                int* __restrict__ marr) {
    int id = blockIdx.x * 256 + threadIdx.x;
    if (id >= NB * NFRAMES) return;
    float best = -3.4e38f; int bidx = 0x7fffffff;
    for (int t = 0; t < 8; ++t) {
        float v = pv[id * 8 + t]; int i = pi[id * 8 + t];
        if (v > best || (v == best && i < bidx)) { best = v; bidx = i; }
    }
    marr[id] = bidx;
}

// ---------------------------------------------------------------- kernel D
// positioned[b,t] += sum_f sum_w wf[f,w] * h_f[(t-w) mod 2n]
// h_f[j] = (1/2n) [ (-1)^j cos(n*theta) + sin(pi*Bj/D)/sin(pi*Aj/D) ]
//   Aj = j*(n+1) - m*n (exact in double), Bj = (2n-1)*Aj, D = 2n(n+1)
__global__ __launch_bounds__(256) void k_shift_acc(const float* __restrict__ wf,
                                                   const int* __restrict__ marr,
                                                   float* __restrict__ outacc) {
    __shared__ __align__(16) float s_h[1540];
    const int tid   = threadIdx.x;
    const int cid   = blockIdx.x;
    const int fg    = cid & 7;
    const int chunk = (cid >> 3) & 31;
    const int b     = cid >> 8;
    const int t0    = chunk * 1024;
    const int f0    = fg * 16;
    const int nf    = (fg == 7) ? 15 : 16;

    float4 acc = make_float4(0.f, 0.f, 0.f, 0.f);
    const double invD = 1.0 / 2147549184.0;   // 1/(65536*32769)

    for (int u = 0; u < nf; ++u) {
        int f  = f0 + u;
        int bf = b * NFRAMES + f;
        const float4* __restrict__ wc = (const float4*)(wf + bf * 512);

        int m = marr[bf];
        double md = (double)m;
        double cosn = cos(md * (M_PI / 32769.0));
        if (m & 1) cosn = -cosn;
        float cosnf = (float)cosn;

        __syncthreads();   // previous frame's conv reads done before re-staging
        for (int e = tid; e < 1540; e += 256) {
            int jj = t0 - 516 + e;
            int j  = jj & 65535;
            double A = (double)j * 32769.0 - md * 32768.0;  // exact integer
            float ratio;
            if (A == 0.0) {
                ratio = 65535.0f;                            // removable 0/0
            } else {
                double rA = A * invD;                        // |rA| < 1.0001
                double kA = rint(rA);
                double dA = rA - kA;
                double rB = (A * 65535.0) * invD;            // exact * invD
                double kB = rint(rB);
                double dB = rB - kB;
                float sA = sinf((float)(dA * M_PI));
                float sB = sinf((float)(dB * M_PI));
                if (((int)kA) & 1) sA = -sA;
                if (((long long)kB) & 1) sB = -sB;
                ratio = sB / sA;
            }
            float sj = (j & 1) ? -1.0f : 1.0f;
            s_h[e] = (1.0f / 65536.0f) * (sj * cosnf + ratio);
        }
        __syncthreads();

        float4 lo = *(float4*)(s_h + 4 * tid + 512);
        float4 hi = *(float4*)(s_h + 4 * tid + 516);
#pragma unroll 8
        for (int g = 0; g < 128; ++g) {
            float4 c = wc[g];
            acc.x = fmaf(c.x, hi.x, acc.x); acc.x = fmaf(c.y, lo.w, acc.x);
            acc.x = fmaf(c.z, lo.z, acc.x); acc.x = fmaf(c.w, lo.y, acc.x);
            acc.y = fmaf(c.x, hi.y, acc.y); acc.y = fmaf(c.y, hi.x, acc.y);
            acc.y = fmaf(c.z, lo.w, acc.y); acc.y = fmaf(c.w, lo.z, acc.y);
            acc.z = fmaf(c.x, hi.z, acc.z); acc.z = fmaf(c.y, hi.y, acc.z);
            acc.z = fmaf(c.z, hi.x, acc.z); acc.z = fmaf(c.w, lo.w, acc.z);
            acc.w = fmaf(c.x, hi.w, acc.w); acc.w = fmaf(c.y, hi.z, acc.w);
            acc.w = fmaf(c.z, hi.y, acc.w); acc.w = fmaf(c.w, hi.x, acc.w);
            hi = lo;
            lo = *(float4*)(s_h + 4 * tid + 508 - 4 * g);
        }
    }

    float* ob = outacc + b * N_SAMP + t0 + 4 * tid;
    atomicAdd(ob + 0, acc.x);
    atomicAdd(ob + 1, acc.y);
    atomicAdd(ob + 2, acc.z);
    atomicAdd(ob + 3, acc.w);
}

// ---------------------------------------------------------------- kernel E
__global__ __launch_bounds__(256) void k_mse(const float* __restrict__ outacc,
                                             const float* __restrict__ tgt,
                                             float* __restrict__ out) {
    __shared__ float sred[4];
    int e = blockIdx.x * 256 + threadIdx.x;
    float d = outacc[e] - tgt[e];
    float v = d * d;
#pragma unroll
    for (int off = 32; off > 0; off >>= 1) v += __shfl_down(v, off, 64);
    int lane = threadIdx.x & 63, wid = threadIdx.x >> 6;
    if (lane == 0) sred[wid] = v;
    __syncthreads();
    if (threadIdx.x == 0) {
        float s = sred[0] + sred[1] + sred[2] + sred[3];
        atomicAdd(out, s * (1.0f / 131072.0f));
    }
}

// ---------------------------------------------------------------- launch
extern "C" void kernel_launch(void* const* d_in, const int* in_sizes, int n_in,
                              void* d_out, int out_size, void* d_ws, size_t ws_size,
                              hipStream_t stream) {
    const float* recon = (const float*)d_in[0];
    const float* tgt   = (const float*)d_in[1];
    float* out = (float*)d_out;
    float* W   = (float*)d_ws;

    float* wf     = W + WS_WF;
    float* pv     = W + WS_PV;
    int*   pi     = (int*)(W + WS_PI);
    int*   marr   = (int*)(W + WS_M);
    float* outacc = W + WS_OUT;

    hipMemsetAsync(out, 0, sizeof(float), stream);
    hipMemsetAsync(outacc, 0, NB * N_SAMP * sizeof(float), stream);

    k_wf<<<(NB * NFRAMES * WINDOW + 255) / 256, 256, 0, stream>>>(recon, wf);
    k_argmax<<<NB * NFRAMES * 8, 256, 0, stream>>>(tgt, wf, pv, pi);
    k_reduce<<<2, 256, 0, stream>>>(pv, pi, marr);
    k_shift_acc<<<1024, 256, 0, stream>>>(wf, marr, outacc);
    k_mse<<<512, 256, 0, stream>>>(outacc, tgt, out);
}

// Round 3
// 544.692 us; speedup vs baseline: 2.1150x; 1.8432x over previous
//
#include <hip/hip_runtime.h>
#include <math.h>

#define N_SAMP   32768
#define WINDOW   512
#define STEP     256
#define NFRAMES  127      // (32768-512)/256 + 1
#define NB       4

// ws layout (float granularity)
#define WS_WF   0               // 4*127*512 = 260096 floats
#define WS_PV   260096          // 4064 floats  (partial max values)
#define WS_PI   264160          // 4064 ints    (partial max indices)
#define WS_M    268224          // 508 ints     (argmax per (b,f))
#define WS_OUT  268736          // 131072 floats (summed positioned)

// XOR swizzle on float4-block index: makes lane-stride-4-block reads an
// 8-phase permutation (same LDS cost as contiguous b128).
#define SW(L) ((L) ^ (((L) >> 3) & 7))

// 16 fma for 4 outputs: c = wf[4g..4g+3], HI = h[base..base+3], LO = h[base-4..base-1]
#define FMA4(A, LO, HI)                                           \
    A.x = fmaf(c.x, HI.x, A.x); A.x = fmaf(c.y, LO.w, A.x);       \
    A.x = fmaf(c.z, LO.z, A.x); A.x = fmaf(c.w, LO.y, A.x);       \
    A.y = fmaf(c.x, HI.y, A.y); A.y = fmaf(c.y, HI.x, A.y);       \
    A.y = fmaf(c.z, LO.w, A.y); A.y = fmaf(c.w, LO.z, A.y);       \
    A.z = fmaf(c.x, HI.z, A.z); A.z = fmaf(c.y, HI.y, A.z);       \
    A.z = fmaf(c.z, HI.x, A.z); A.z = fmaf(c.w, LO.w, A.z);       \
    A.w = fmaf(c.x, HI.w, A.w); A.w = fmaf(c.y, HI.z, A.w);       \
    A.w = fmaf(c.z, HI.y, A.w); A.w = fmaf(c.w, HI.x, A.w);

#define LDBLK(SH, n) (*(const float4*)((SH) + 4 * SW(Lb + (n))))

// one conv step g: window slots S0..S4 hold blocks n0..n0+4 (n0 = 127-g).
// prefetch block n0-1 into temp, 64 FMAs, then rotate into vacated slot S4.
#define CBODY(SH, g, S0, S1, S2, S3, S4)                          \
    {                                                             \
        float4 tnew = LDBLK(SH, 127 - (g) - 1);                   \
        const float4 c = wc[(g)];                                 \
        FMA4(acc0, w[S0], w[S1]); FMA4(acc1, w[S1], w[S2]);       \
        FMA4(acc2, w[S2], w[S3]); FMA4(acc3, w[S3], w[S4]);       \
        w[S4] = tnew;                                             \
    }
#define CBODY_NL(g, S0, S1, S2, S3, S4)                           \
    {                                                             \
        const float4 c = wc[(g)];                                 \
        FMA4(acc0, w[S0], w[S1]); FMA4(acc1, w[S1], w[S2]);       \
        FMA4(acc2, w[S2], w[S3]); FMA4(acc3, w[S3], w[S4]);       \
    }

// ---------------------------------------------------------------- kernel A
__global__ __launch_bounds__(256) void k_wf(const float* __restrict__ recon,
                                            float* __restrict__ wf) {
    int e = blockIdx.x * 256 + threadIdx.x;
    if (e >= NB * NFRAMES * WINDOW) return;
    int w  = e & 511;
    int bf = e >> 9;
    int f  = bf % NFRAMES;
    int b  = bf / NFRAMES;
    float ham = 0.54f - 0.46f * (float)cos((double)w * (M_PI / 256.0));
    wf[e] = ham * recon[b * N_SAMP + f * STEP + w];
}

// ---------------------------------------------------------------- kernel B
// fm[t] = sum_w wf[w]*tgt[t-w]; per-block argmax over a 4096-chunk.
// 16 outputs/thread; swizzled LDS; coefficients via scalar-cached global.
__global__ __launch_bounds__(256) void k_argmax(const float* __restrict__ tgt,
                                                const float* __restrict__ wf,
                                                float* __restrict__ pv,
                                                int*   __restrict__ pi) {
    __shared__ __align__(16) float s_tg[4608];   // blocks [t0-512, t0+4096)
    __shared__ float rv[256];
    __shared__ int   ri[256];
    const int tid  = threadIdx.x;
    const int tile = blockIdx.x & 7;
    const int bf   = blockIdx.x >> 3;
    const int b    = bf / NFRAMES;
    const float* tb = tgt + b * N_SAMP;
    const float4* __restrict__ wc = (const float4*)(wf + bf * 512);
    const int t0 = tile * 4096;
    const int Lb = 4 * tid;

    for (int e4 = tid; e4 < 1152; e4 += 256) {
        int g = t0 - 512 + 4 * e4;
        float4 v;
        if (g >= 0) v = *(const float4*)(tb + g);
        else        v = make_float4(0.f, 0.f, 0.f, 0.f);
        *(float4*)(s_tg + 4 * SW(e4)) = v;
    }
    __syncthreads();

    float4 acc0 = make_float4(0.f, 0.f, 0.f, 0.f);
    float4 acc1 = acc0, acc2 = acc0, acc3 = acc0;
    float4 w[5];
    w[2] = LDBLK(s_tg, 127); w[3] = LDBLK(s_tg, 128);
    w[4] = LDBLK(s_tg, 129); w[0] = LDBLK(s_tg, 130);
    w[1] = LDBLK(s_tg, 131);
    for (int go = 0; go < 25; ++go) {
        const int gb = 5 * go;
        CBODY(s_tg, gb + 0, 2, 3, 4, 0, 1);
        CBODY(s_tg, gb + 1, 1, 2, 3, 4, 0);
        CBODY(s_tg, gb + 2, 0, 1, 2, 3, 4);
        CBODY(s_tg, gb + 3, 4, 0, 1, 2, 3);
        CBODY(s_tg, gb + 4, 3, 4, 0, 1, 2);
    }
    CBODY(s_tg, 125, 2, 3, 4, 0, 1);
    CBODY(s_tg, 126, 1, 2, 3, 4, 0);
    CBODY_NL(   127, 0, 1, 2, 3, 4);

    float best = -3.4e38f;
    int   bidx = 0;
    const int tbase = t0 + 16 * tid;
#define AMX(v, i) if ((v) > best) { best = (v); bidx = (i); }
    AMX(acc0.x, tbase + 0)  AMX(acc0.y, tbase + 1)
    AMX(acc0.z, tbase + 2)  AMX(acc0.w, tbase + 3)
    AMX(acc1.x, tbase + 4)  AMX(acc1.y, tbase + 5)
    AMX(acc1.z, tbase + 6)  AMX(acc1.w, tbase + 7)
    AMX(acc2.x, tbase + 8)  AMX(acc2.y, tbase + 9)
    AMX(acc2.z, tbase + 10) AMX(acc2.w, tbase + 11)
    AMX(acc3.x, tbase + 12) AMX(acc3.y, tbase + 13)
    AMX(acc3.z, tbase + 14) AMX(acc3.w, tbase + 15)
#undef AMX

    rv[tid] = best; ri[tid] = bidx;
    __syncthreads();
    for (int s = 128; s > 0; s >>= 1) {
        if (tid < s) {
            float v2 = rv[tid + s]; int i2 = ri[tid + s];
            if (v2 > rv[tid] || (v2 == rv[tid] && i2 < ri[tid])) {
                rv[tid] = v2; ri[tid] = i2;
            }
        }
        __syncthreads();
    }
    if (tid == 0) { pv[blockIdx.x] = rv[0]; pi[blockIdx.x] = ri[0]; }
}

// ---------------------------------------------------------------- kernel C
__global__ __launch_bounds__(256) void k_reduce(const float* __restrict__ pv,
                                                const int* __restrict__ pi,
                                                int* __restrict__ marr) {
    int id = blockIdx.x * 256 + threadIdx.x;
    if (id >= NB * NFRAMES) return;
    float best = -3.4e38f; int bidx = 0x7fffffff;
    for (int t = 0; t < 8; ++t) {
        float v = pv[id * 8 + t]; int i = pi[id * 8 + t];
        if (v > best || (v == best && i < bidx)) { best = v; bidx = i; }
    }
    marr[id] = bidx;
}

// ---------------------------------------------------------------- kernel D
// h_f[j] = (1/2n)[(-1)^j cos(n*theta) + sin(pi*Bj/D)/sin(pi*Aj/D)]
__device__ __forceinline__ float hval(int j, double md, float cosnf) {
    const double invD = 1.0 / 2147549184.0;   // 1/(65536*32769)
    double A = (double)j * 32769.0 - md * 32768.0;  // exact integer
    float ratio;
    if (A == 0.0) {
        ratio = 65535.0f;
    } else {
        double rA = A * invD;
        double kA = rint(rA);
        double dA = rA - kA;
        double rB = (A * 65535.0) * invD;
        double kB = rint(rB);
        double dB = rB - kB;
        float sA = sinf((float)(dA * M_PI));
        float sB = sinf((float)(dB * M_PI));
        if (((int)kA) & 1) sA = -sA;
        if (((long long)kB) & 1) sB = -sB;
        ratio = sB / sA;
    }
    float sj = (j & 1) ? -1.0f : 1.0f;
    return (1.0f / 65536.0f) * (sj * cosnf + ratio);
}

__global__ __launch_bounds__(256) void k_shift_acc(const float* __restrict__ wf,
                                                   const int* __restrict__ marr,
                                                   float* __restrict__ outacc) {
    __shared__ __align__(16) float s_h[4608];    // blocks [t0-512, t0+4096)
    const int tid   = threadIdx.x;
    const int cid   = blockIdx.x;
    const int fg    = cid & 31;                  // 32 frame groups of 4
    const int chunk = (cid >> 5) & 7;
    const int b     = cid >> 8;
    const int t0    = chunk * 4096;
    const int f0    = fg * 4;
    const int nf    = (f0 + 4 <= NFRAMES) ? 4 : (NFRAMES - f0);
    const int Lb    = 4 * tid;

    float4 acc0 = make_float4(0.f, 0.f, 0.f, 0.f);
    float4 acc1 = acc0, acc2 = acc0, acc3 = acc0;

    for (int u = 0; u < nf; ++u) {
        int bf = b * NFRAMES + f0 + u;
        const float4* __restrict__ wc = (const float4*)(wf + bf * 512);

        int m = marr[bf];
        double md = (double)m;
        double cosn = cos(md * (M_PI / 32769.0));
        if (m & 1) cosn = -cosn;
        float cosnf = (float)cosn;

        __syncthreads();   // previous frame's conv reads done before re-staging
        for (int e4 = tid; e4 < 1152; e4 += 256) {
            int j0 = t0 - 512 + 4 * e4;
            float4 v;
            v.x = hval((j0 + 0) & 65535, md, cosnf);
            v.y = hval((j0 + 1) & 65535, md, cosnf);
            v.z = hval((j0 + 2) & 65535, md, cosnf);
            v.w = hval((j0 + 3) & 65535, md, cosnf);
            *(float4*)(s_h + 4 * SW(e4)) = v;
        }
        __syncthreads();

        float4 w[5];
        w[2] = LDBLK(s_h, 127); w[3] = LDBLK(s_h, 128);
        w[4] = LDBLK(s_h, 129); w[0] = LDBLK(s_h, 130);
        w[1] = LDBLK(s_h, 131);
        for (int go = 0; go < 25; ++go) {
            const int gb = 5 * go;
            CBODY(s_h, gb + 0, 2, 3, 4, 0, 1);
            CBODY(s_h, gb + 1, 1, 2, 3, 4, 0);
            CBODY(s_h, gb + 2, 0, 1, 2, 3, 4);
            CBODY(s_h, gb + 3, 4, 0, 1, 2, 3);
            CBODY(s_h, gb + 4, 3, 4, 0, 1, 2);
        }
        CBODY(s_h, 125, 2, 3, 4, 0, 1);
        CBODY(s_h, 126, 1, 2, 3, 4, 0);
        CBODY_NL(   127, 0, 1, 2, 3, 4);
    }

    float* ob = outacc + b * N_SAMP + t0 + 16 * tid;
    atomicAdd(ob + 0,  acc0.x); atomicAdd(ob + 1,  acc0.y);
    atomicAdd(ob + 2,  acc0.z); atomicAdd(ob + 3,  acc0.w);
    atomicAdd(ob + 4,  acc1.x); atomicAdd(ob + 5,  acc1.y);
    atomicAdd(ob + 6,  acc1.z); atomicAdd(ob + 7,  acc1.w);
    atomicAdd(ob + 8,  acc2.x); atomicAdd(ob + 9,  acc2.y);
    atomicAdd(ob + 10, acc2.z); atomicAdd(ob + 11, acc2.w);
    atomicAdd(ob + 12, acc3.x); atomicAdd(ob + 13, acc3.y);
    atomicAdd(ob + 14, acc3.z); atomicAdd(ob + 15, acc3.w);
}

// ---------------------------------------------------------------- kernel E
__global__ __launch_bounds__(256) void k_mse(const float* __restrict__ outacc,
                                             const float* __restrict__ tgt,
                                             float* __restrict__ out) {
    __shared__ float sred[4];
    int e = blockIdx.x * 256 + threadIdx.x;
    float d = outacc[e] - tgt[e];
    float v = d * d;
#pragma unroll
    for (int off = 32; off > 0; off >>= 1) v += __shfl_down(v, off, 64);
    int lane = threadIdx.x & 63, wid = threadIdx.x >> 6;
    if (lane == 0) sred[wid] = v;
    __syncthreads();
    if (threadIdx.x == 0) {
        float s = sred[0] + sred[1] + sred[2] + sred[3];
        atomicAdd(out, s * (1.0f / 131072.0f));
    }
}

// ---------------------------------------------------------------- launch
extern "C" void kernel_launch(void* const* d_in, const int* in_sizes, int n_in,
                              void* d_out, int out_size, void* d_ws, size_t ws_size,
                              hipStream_t stream) {
    const float* recon = (const float*)d_in[0];
    const float* tgt   = (const float*)d_in[1];
    float* out = (float*)d_out;
    float* W   = (float*)d_ws;

    float* wf     = W + WS_WF;
    float* pv     = W + WS_PV;
    int*   pi     = (int*)(W + WS_PI);
    int*   marr   = (int*)(W + WS_M);
    float* outacc = W + WS_OUT;

    hipMemsetAsync(out, 0, sizeof(float), stream);
    hipMemsetAsync(outacc, 0, NB * N_SAMP * sizeof(float), stream);

    k_wf<<<(NB * NFRAMES * WINDOW + 255) / 256, 256, 0, stream>>>(recon, wf);
    k_argmax<<<NB * NFRAMES * 8, 256, 0, stream>>>(tgt, wf, pv, pi);
    k_reduce<<<2, 256, 0, stream>>>(pv, pi, marr);
    k_shift_acc<<<1024, 256, 0, stream>>>(wf, marr, outacc);
    k_mse<<<512, 256, 0, stream>>>(outacc, tgt, out);
}

// Round 4
// 436.283 us; speedup vs baseline: 2.6405x; 1.2485x over previous
//
#include <hip/hip_runtime.h>
#include <math.h>

#define N_SAMP   32768
#define WINDOW   512
#define STEP     256
#define NFRAMES  127      // (32768-512)/256 + 1
#define NB       4
#define NFG      16       // frame groups in k_shift_acc (8 frames each)

// ws layout (float granularity)
#define WS_WF   0               // 4*127*512 = 260096 floats
#define WS_PV   260096          // 4064 floats  (partial max values)
#define WS_PI   264160          // 4064 ints    (partial max indices)
#define WS_M    268224          // 508 ints     (argmax per (b,f))
#define WS_PART 268736          // 16*4*32768 = 2097152 floats (per-fg partials)

// XOR swizzle on float4-block index: makes lane-stride-4-block reads an
// 8-phase permutation (same LDS cost as contiguous b128).
#define SW(L) ((L) ^ (((L) >> 3) & 7))

// 16 fma for 4 outputs: c = wf[4g..4g+3], HI = h[base..base+3], LO = h[base-4..base-1]
#define FMA4(A, LO, HI)                                           \
    A.x = fmaf(c.x, HI.x, A.x); A.x = fmaf(c.y, LO.w, A.x);       \
    A.x = fmaf(c.z, LO.z, A.x); A.x = fmaf(c.w, LO.y, A.x);       \
    A.y = fmaf(c.x, HI.y, A.y); A.y = fmaf(c.y, HI.x, A.y);       \
    A.y = fmaf(c.z, LO.w, A.y); A.y = fmaf(c.w, LO.z, A.y);       \
    A.z = fmaf(c.x, HI.z, A.z); A.z = fmaf(c.y, HI.y, A.z);       \
    A.z = fmaf(c.z, HI.x, A.z); A.z = fmaf(c.w, LO.w, A.z);       \
    A.w = fmaf(c.x, HI.w, A.w); A.w = fmaf(c.y, HI.z, A.w);       \
    A.w = fmaf(c.z, HI.y, A.w); A.w = fmaf(c.w, HI.x, A.w);

#define LDBLK(SH, n) (*(const float4*)((SH) + 4 * SW(Lb + (n))))

#define CBODY(SH, g, S0, S1, S2, S3, S4)                          \
    {                                                             \
        float4 tnew = LDBLK(SH, 127 - (g) - 1);                   \
        const float4 c = wc[(g)];                                 \
        FMA4(acc0, w[S0], w[S1]); FMA4(acc1, w[S1], w[S2]);       \
        FMA4(acc2, w[S2], w[S3]); FMA4(acc3, w[S3], w[S4]);       \
        w[S4] = tnew;                                             \
    }
#define CBODY_NL(g, S0, S1, S2, S3, S4)                           \
    {                                                             \
        const float4 c = wc[(g)];                                 \
        FMA4(acc0, w[S0], w[S1]); FMA4(acc1, w[S1], w[S2]);       \
        FMA4(acc2, w[S2], w[S3]); FMA4(acc3, w[S3], w[S4]);       \
    }

#define CONV512(SH)                                               \
    {                                                             \
        float4 w[5];                                              \
        w[2] = LDBLK(SH, 127); w[3] = LDBLK(SH, 128);             \
        w[4] = LDBLK(SH, 129); w[0] = LDBLK(SH, 130);             \
        w[1] = LDBLK(SH, 131);                                    \
        for (int go = 0; go < 25; ++go) {                         \
            const int gb = 5 * go;                                \
            CBODY(SH, gb + 0, 2, 3, 4, 0, 1);                     \
            CBODY(SH, gb + 1, 1, 2, 3, 4, 0);                     \
            CBODY(SH, gb + 2, 0, 1, 2, 3, 4);                     \
            CBODY(SH, gb + 3, 4, 0, 1, 2, 3);                     \
            CBODY(SH, gb + 4, 3, 4, 0, 1, 2);                     \
        }                                                         \
        CBODY(SH, 125, 2, 3, 4, 0, 1);                            \
        CBODY(SH, 126, 1, 2, 3, 4, 0);                            \
        CBODY_NL(   127, 0, 1, 2, 3, 4);                          \
    }

// ---------------------------------------------------------------- kernel A
__global__ __launch_bounds__(256) void k_wf(const float* __restrict__ recon,
                                            float* __restrict__ wf) {
    int e = blockIdx.x * 256 + threadIdx.x;
    if (e >= NB * NFRAMES * WINDOW) return;
    int w  = e & 511;
    int bf = e >> 9;
    int f  = bf % NFRAMES;
    int b  = bf / NFRAMES;
    float ham = 0.54f - 0.46f * (float)cos((double)w * (M_PI / 256.0));
    wf[e] = ham * recon[b * N_SAMP + f * STEP + w];
}

// ---------------------------------------------------------------- kernel B
__global__ __launch_bounds__(256) void k_argmax(const float* __restrict__ tgt,
                                                const float* __restrict__ wf,
                                                float* __restrict__ pv,
                                                int*   __restrict__ pi) {
    __shared__ __align__(16) float s_tg[4608];   // blocks [t0-512, t0+4096)
    __shared__ float rv[256];
    __shared__ int   ri[256];
    const int tid  = threadIdx.x;
    const int tile = blockIdx.x & 7;
    const int bf   = blockIdx.x >> 3;
    const int b    = bf / NFRAMES;
    const float* tb = tgt + b * N_SAMP;
    const float4* __restrict__ wc = (const float4*)(wf + bf * 512);
    const int t0 = tile * 4096;
    const int Lb = 4 * tid;

    for (int e4 = tid; e4 < 1152; e4 += 256) {
        int g = t0 - 512 + 4 * e4;
        float4 v;
        if (g >= 0) v = *(const float4*)(tb + g);
        else        v = make_float4(0.f, 0.f, 0.f, 0.f);
        *(float4*)(s_tg + 4 * SW(e4)) = v;
    }
    __syncthreads();

    float4 acc0 = make_float4(0.f, 0.f, 0.f, 0.f);
    float4 acc1 = acc0, acc2 = acc0, acc3 = acc0;
    CONV512(s_tg)

    float best = -3.4e38f;
    int   bidx = 0;
    const int tbase = t0 + 16 * tid;
#define AMX(v, i) if ((v) > best) { best = (v); bidx = (i); }
    AMX(acc0.x, tbase + 0)  AMX(acc0.y, tbase + 1)
    AMX(acc0.z, tbase + 2)  AMX(acc0.w, tbase + 3)
    AMX(acc1.x, tbase + 4)  AMX(acc1.y, tbase + 5)
    AMX(acc1.z, tbase + 6)  AMX(acc1.w, tbase + 7)
    AMX(acc2.x, tbase + 8)  AMX(acc2.y, tbase + 9)
    AMX(acc2.z, tbase + 10) AMX(acc2.w, tbase + 11)
    AMX(acc3.x, tbase + 12) AMX(acc3.y, tbase + 13)
    AMX(acc3.z, tbase + 14) AMX(acc3.w, tbase + 15)
#undef AMX

    rv[tid] = best; ri[tid] = bidx;
    __syncthreads();
    for (int s = 128; s > 0; s >>= 1) {
        if (tid < s) {
            float v2 = rv[tid + s]; int i2 = ri[tid + s];
            if (v2 > rv[tid] || (v2 == rv[tid] && i2 < ri[tid])) {
                rv[tid] = v2; ri[tid] = i2;
            }
        }
        __syncthreads();
    }
    if (tid == 0) { pv[blockIdx.x] = rv[0]; pi[blockIdx.x] = ri[0]; }
}

// ---------------------------------------------------------------- kernel C
__global__ __launch_bounds__(256) void k_reduce(const float* __restrict__ pv,
                                                const int* __restrict__ pi,
                                                int* __restrict__ marr) {
    int id = blockIdx.x * 256 + threadIdx.x;
    if (id >= NB * NFRAMES) return;
    float best = -3.4e38f; int bidx = 0x7fffffff;
    for (int t = 0; t < 8; ++t) {
        float v = pv[id * 8 + t]; int i = pi[id * 8 + t];
        if (v > best || (v == best && i < bidx)) { best = v; bidx = i; }
    }
    marr[id] = bidx;
}

// ---------------------------------------------------------------- kernel D
// Closed form: with psi = pi*m/32769, A_j = j*32769 - m*32768, D = 65536*32769,
//   h[j] = (-1)^(j+m) * (sin(psi)/65536) * cot(pi * frac(A_j/D))
// (cot is pi-periodic -> no mod-sign bookkeeping). m==0 -> h = delta at j=0.
__global__ __launch_bounds__(256) void k_shift_acc(const float* __restrict__ wf,
                                                   const int* __restrict__ marr,
                                                   float* __restrict__ part) {
    __shared__ __align__(16) float s_h[4608];    // blocks [t0-512, t0+4096)
    const int tid   = threadIdx.x;
    const int cid   = blockIdx.x;
    const int fg    = cid & 15;                  // 16 frame groups of 8
    const int chunk = (cid >> 4) & 7;
    const int b     = cid >> 7;
    const int t0    = chunk * 4096;
    const int f0    = fg * 8;
    const int nf    = (fg == 15) ? 7 : 8;
    const int Lb    = 4 * tid;

    float4 acc0 = make_float4(0.f, 0.f, 0.f, 0.f);
    float4 acc1 = acc0, acc2 = acc0, acc3 = acc0;
    const double invD = 1.0 / 2147549184.0;   // 1/(65536*32769)

    for (int u = 0; u < nf; ++u) {
        int bf = b * NFRAMES + f0 + u;
        const float4* __restrict__ wc = (const float4*)(wf + bf * 512);

        int m = marr[bf];
        double md32768 = (double)m * 32768.0;
        double sp = sin((double)m * (M_PI / 32769.0));
        float Cp = (float)(sp * (1.0 / 65536.0));
        if (m & 1) Cp = -Cp;
        float Cn = -Cp;    // odd-j elements

        __syncthreads();   // previous frame's conv reads done before re-staging
        if (m == 0) {
            for (int e4 = tid; e4 < 1152; e4 += 256) {
                int j0 = t0 - 512 + 4 * e4;
                float4 v;
                v.x = (j0 == 0) ? 1.0f : 0.0f;      // j0+1..3 never 0 (j0 mult of 4)
                v.y = 0.0f; v.z = 0.0f; v.w = 0.0f;
                *(float4*)(s_h + 4 * SW(e4)) = v;
            }
        } else {
            for (int e4 = tid; e4 < 1152; e4 += 256) {
                int j0 = t0 - 512 + 4 * e4;         // j0 always even
                double A0 = (double)j0 * 32769.0 - md32768;   // exact integer
                float4 v;
#pragma unroll
                for (int k = 0; k < 4; ++k) {
                    double rA = (A0 + (double)k * 32769.0) * invD;
                    float f = (float)(rA - rint(rA));
                    float s, c;
                    __sincosf((float)M_PI * f, &s, &c);
                    float r = c * __builtin_amdgcn_rcpf(s);
                    ((float*)&v)[k] = ((k & 1) ? Cn : Cp) * r;
                }
                *(float4*)(s_h + 4 * SW(e4)) = v;
            }
        }
        __syncthreads();

        CONV512(s_h)
    }

    float* ob = part + fg * (NB * N_SAMP) + b * N_SAMP + t0 + 16 * tid;
    *(float4*)(ob + 0)  = acc0;
    *(float4*)(ob + 4)  = acc1;
    *(float4*)(ob + 8)  = acc2;
    *(float4*)(ob + 12) = acc3;
}

// ---------------------------------------------------------------- kernel E
// sum the 16 per-fg partials, then MSE against target
__global__ __launch_bounds__(256) void k_mse(const float* __restrict__ part,
                                             const float* __restrict__ tgt,
                                             float* __restrict__ out) {
    __shared__ float sred[4];
    int e = blockIdx.x * 256 + threadIdx.x;
    float s = 0.f;
#pragma unroll
    for (int g = 0; g < NFG; ++g) s += part[g * (NB * N_SAMP) + e];
    float d = s - tgt[e];
    float v = d * d;
#pragma unroll
    for (int off = 32; off > 0; off >>= 1) v += __shfl_down(v, off, 64);
    int lane = threadIdx.x & 63, wid = threadIdx.x >> 6;
    if (lane == 0) sred[wid] = v;
    __syncthreads();
    if (threadIdx.x == 0) {
        float sm = sred[0] + sred[1] + sred[2] + sred[3];
        atomicAdd(out, sm * (1.0f / 131072.0f));
    }
}

// ---------------------------------------------------------------- launch
extern "C" void kernel_launch(void* const* d_in, const int* in_sizes, int n_in,
                              void* d_out, int out_size, void* d_ws, size_t ws_size,
                              hipStream_t stream) {
    const float* recon = (const float*)d_in[0];
    const float* tgt   = (const float*)d_in[1];
    float* out = (float*)d_out;
    float* W   = (float*)d_ws;

    float* wf   = W + WS_WF;
    float* pv   = W + WS_PV;
    int*   pi   = (int*)(W + WS_PI);
    int*   marr = (int*)(W + WS_M);
    float* part = W + WS_PART;

    hipMemsetAsync(out, 0, sizeof(float), stream);

    k_wf<<<(NB * NFRAMES * WINDOW + 255) / 256, 256, 0, stream>>>(recon, wf);
    k_argmax<<<NB * NFRAMES * 8, 256, 0, stream>>>(tgt, wf, pv, pi);
    k_reduce<<<2, 256, 0, stream>>>(pv, pi, marr);
    k_shift_acc<<<NB * 8 * NFG, 256, 0, stream>>>(wf, marr, part);
    k_mse<<<512, 256, 0, stream>>>(part, tgt, out);
}